// Round 6
// baseline (569.554 us; speedup 1.0000x reference)
//
#include <hip/hip_runtime.h>
#include <hip/hip_bf16.h>

#define NNODE 50000
#define DIM   256
#define EDGES 400000
#define NET   4
#define NTOT  (NET * NNODE)          // 200000
#define BSH   7
#define NBUCK ((NTOT + 127) >> BSH)  // 1563
#define EPB2  8192                   // edges per chunk
#define CPE   49                     // chunks per etype (49*8192 >= 400000)
#define NBLKT (CPE * NET)            // 196 chunk-blocks total
#define NSCAN (NBUCK * NBLKT)        // 306348

#define AS1 __attribute__((address_space(1)))
#define AS3 __attribute__((address_space(3)))

typedef __attribute__((ext_vector_type(8))) __bf16 bf16x8;
typedef __attribute__((ext_vector_type(4))) float f32x4;
typedef __attribute__((ext_vector_type(4))) unsigned short u16x4;
typedef __attribute__((ext_vector_type(8))) unsigned short u16x8;

__device__ __forceinline__ float bf2f(unsigned short u) {
  unsigned int x = ((unsigned int)u) << 16;
  return __builtin_bit_cast(float, x);
}
__device__ __forceinline__ unsigned short f2bf(float f) {
  __hip_bfloat16 h = __float2bfloat16(f);   // RTNE
  return __builtin_bit_cast(unsigned short, h);
}

__global__ void conv_f32_bf16(const float* __restrict__ in, unsigned short* __restrict__ out, int n4) {
  int i = blockIdx.x * blockDim.x + threadIdx.x;
  if (i >= n4) return;
  f32x4 v = reinterpret_cast<const f32x4*>(in)[i];
  u16x4 o;
  o[0] = f2bf(v[0]); o[1] = f2bf(v[1]); o[2] = f2bf(v[2]); o[3] = f2bf(v[3]);
  reinterpret_cast<u16x4*>(out)[i] = o;
}

// Build 3 stacked-K transposed weight matrices: T[n][k] with k<256 from A, k>=256 from B.
__global__ void conv_wT3(const float* __restrict__ a0, const float* __restrict__ b0,
                         const float* __restrict__ a1, const float* __restrict__ b1,
                         const float* __restrict__ a2, const float* __restrict__ b2,
                         unsigned short* __restrict__ t0, unsigned short* __restrict__ t1,
                         unsigned short* __restrict__ t2) {
  int m = blockIdx.y;
  const float* A = (m == 0) ? a0 : (m == 1) ? a1 : a2;
  const float* B = (m == 0) ? b0 : (m == 1) ? b1 : b2;
  unsigned short* T = (m == 0) ? t0 : (m == 1) ? t1 : t2;
  int n = blockIdx.x, k = threadIdx.x;   // 256 threads
  T[n * 512 + k]       = f2bf(A[k * 256 + n]);
  T[n * 512 + 256 + k] = f2bf(B[k * 256 + n]);
}

__global__ void fill_f32(float* __restrict__ p, float v, int n) {
  int i = blockIdx.x * blockDim.x + threadIdx.x;
  if (i < n) p[i] = v;
}

// ---- multi-split CSR build: no per-edge global atomics ----
__global__ void hist_ms(const int* __restrict__ d0, const int* __restrict__ d1,
                        const int* __restrict__ d2, const int* __restrict__ d3,
                        int* __restrict__ cnt) {
  __shared__ int h[NBUCK];
  for (int i = threadIdx.x; i < NBUCK; i += 256) h[i] = 0;
  __syncthreads();
  int t = blockIdx.y, cx = blockIdx.x;
  const int* dp = (t == 0) ? d0 : (t == 1) ? d1 : (t == 2) ? d2 : d3;
  int base = cx * EPB2;
  int lim = base + EPB2; if (lim > EDGES) lim = EDGES;
  for (int i = base + threadIdx.x; i < lim; i += 256)
    atomicAdd(&h[(t * NNODE + dp[i]) >> BSH], 1);
  __syncthreads();
  int blk = t * CPE + cx;
  for (int i = threadIdx.x; i < NBUCK; i += 256)
    cnt[i * NBLKT + blk] = h[i];
}

__global__ void scan_p1(const int* __restrict__ data, int* __restrict__ bsum, int n) {
  __shared__ int red[256];
  int base = blockIdx.x * 4096;
  int s = 0;
  #pragma unroll
  for (int j = 0; j < 16; j++) {
    int idx = base + j * 256 + threadIdx.x;
    s += (idx < n) ? data[idx] : 0;
  }
  red[threadIdx.x] = s;
  __syncthreads();
  for (int o = 128; o > 0; o >>= 1) {
    if (threadIdx.x < o) red[threadIdx.x] += red[threadIdx.x + o];
    __syncthreads();
  }
  if (threadIdx.x == 0) bsum[blockIdx.x] = red[0];
}

__global__ void scan_p2(int* __restrict__ bsum, int nb, int* __restrict__ off, int nscan,
                        int* __restrict__ S) {
  __shared__ int sh[128];
  int tid = threadIdx.x;
  int v = (tid < nb) ? bsum[tid] : 0;
  sh[tid] = v;
  __syncthreads();
  for (int o = 1; o < 128; o <<= 1) {
    int a = (tid >= o) ? sh[tid - o] : 0;
    __syncthreads();
    sh[tid] += a;
    __syncthreads();
  }
  if (tid < nb) bsum[tid] = sh[tid] - v;   // exclusive block bases
  if (tid == 0) { off[nscan] = sh[127]; S[NTOT] = sh[127]; }
}

__global__ void scan_p3(int* __restrict__ data, const int* __restrict__ bsum, int n) {
  __shared__ int sh[256];
  int tid = threadIdx.x;
  int base = blockIdx.x * 4096 + tid * 16;
  int vals[16];
  int s = 0;
  #pragma unroll
  for (int j = 0; j < 16; j++) {
    vals[j] = (base + j < n) ? data[base + j] : 0;
    s += vals[j];
  }
  sh[tid] = s;
  __syncthreads();
  for (int o = 1; o < 256; o <<= 1) {
    int a = (tid >= o) ? sh[tid - o] : 0;
    __syncthreads();
    sh[tid] += a;
    __syncthreads();
  }
  int run = bsum[blockIdx.x] + sh[tid] - s;
  #pragma unroll
  for (int j = 0; j < 16; j++) {
    if (base + j < n) { data[base + j] = run; run += vals[j]; }
  }
}

__global__ void scatter_ms(const int* __restrict__ s0, const int* __restrict__ s1,
                           const int* __restrict__ s2, const int* __restrict__ s3,
                           const int* __restrict__ d0, const int* __restrict__ d1,
                           const int* __restrict__ d2, const int* __restrict__ d3,
                           const int* __restrict__ off, unsigned int* __restrict__ pairs) {
  __shared__ int cur[NBUCK];
  int t = blockIdx.y, cx = blockIdx.x;
  int blk = t * CPE + cx;
  for (int i = threadIdx.x; i < NBUCK; i += 256)
    cur[i] = off[i * NBLKT + blk];
  __syncthreads();
  const int* sp = (t == 0) ? s0 : (t == 1) ? s1 : (t == 2) ? s2 : s3;
  const int* dp = (t == 0) ? d0 : (t == 1) ? d1 : (t == 2) ? d2 : d3;
  int base = cx * EPB2;
  int lim = base + EPB2; if (lim > EDGES) lim = EDGES;
  for (int i = base + threadIdx.x; i < lim; i += 256) {
    int key = t * NNODE + dp[i];
    int slot = atomicAdd(&cur[key >> BSH], 1);
    pairs[slot] = ((unsigned int)(key & 127) << 16) | (unsigned int)sp[i];
  }
}

__global__ void bucket_final(const int* __restrict__ off, const unsigned int* __restrict__ pairs,
                             int* __restrict__ S, int* __restrict__ srcs) {
  __shared__ int lcnt[128];
  __shared__ int loff[128];
  int b = blockIdx.x;
  int tid = threadIdx.x;
  int beg = off[b * NBLKT], end = off[(b + 1) * NBLKT];
  if (tid < 128) lcnt[tid] = 0;
  __syncthreads();
  for (int e = beg + tid; e < end; e += 256)
    atomicAdd(&lcnt[pairs[e] >> 16], 1);
  __syncthreads();
  int c = (tid < 128) ? lcnt[tid] : 0;
  if (tid < 128) loff[tid] = c;
  __syncthreads();
  for (int o = 1; o < 128; o <<= 1) {
    int a = (tid < 128 && tid >= o) ? loff[tid - o] : 0;
    __syncthreads();
    if (tid < 128) loff[tid] += a;
    __syncthreads();
  }
  if (tid < 128) {
    int ex = loff[tid] - c;
    int key = (b << BSH) + tid;
    if (key < NTOT) S[key] = beg + ex;
    lcnt[tid] = ex;                   // running cursor
  }
  __syncthreads();
  for (int e = beg + tid; e < end; e += 256) {
    unsigned int p = pairs[e];
    int lk = p >> 16;
    int slot = beg + atomicAdd(&lcnt[lk], 1);
    srcs[slot] = (int)(p & 0xFFFFu);
  }
}

// ---- aggregation: mean of src features per (etype, dst). Two etypes fused.
__device__ __forceinline__ void agg_loop(const int* __restrict__ srcs, int e0, int e1,
                                         int half, int l5,
                                         const unsigned short* __restrict__ feat, float* acc) {
  int e = e0 + half;
  u16x8 v = {};
  if (e < e1) v = *reinterpret_cast<const u16x8*>(feat + (size_t)srcs[e] * 256 + l5 * 8);
  while (e < e1) {
    u16x8 cur = v;
    e += 2;
    if (e < e1) v = *reinterpret_cast<const u16x8*>(feat + (size_t)srcs[e] * 256 + l5 * 8);
    #pragma unroll
    for (int j = 0; j < 8; j++) acc[j] += bf2f(cur[j]);
  }
}

__global__ __launch_bounds__(256) void agg_pair(
    const int* __restrict__ S, const int* __restrict__ srcs,
    const unsigned short* __restrict__ featA, int etA, unsigned short* __restrict__ outA,
    const unsigned short* __restrict__ featB, int etB, unsigned short* __restrict__ outB)
{
  int d = blockIdx.x * 4 + (threadIdx.x >> 6);
  int lane = threadIdx.x & 63;
  int half = lane >> 5, l5 = lane & 31;

  float accA[8] = {0,0,0,0,0,0,0,0}, accB[8] = {0,0,0,0,0,0,0,0};
  int gA = etA * NNODE + d;
  int a0 = S[gA], a1 = S[gA + 1];
  agg_loop(srcs, a0, a1, half, l5, featA, accA);
  int gB = etB * NNODE + d;
  int b0 = S[gB], b1 = S[gB + 1];
  agg_loop(srcs, b0, b1, half, l5, featB, accB);

  #pragma unroll
  for (int j = 0; j < 8; j++) {
    accA[j] += __shfl_xor(accA[j], 32);
    accB[j] += __shfl_xor(accB[j], 32);
  }
  float dA = (float)(a1 - a0); if (dA < 1.f) dA = 1.f;
  float dB = (float)(b1 - b0); if (dB < 1.f) dB = 1.f;
  float invA = 1.f / dA, invB = 1.f / dB;

  u16x8 o;
  if (half == 0) {
    #pragma unroll
    for (int j = 0; j < 8; j++) o[j] = f2bf(accA[j] * invA);
    *reinterpret_cast<u16x8*>(outA + (size_t)d * 256 + l5 * 8) = o;
  } else {
    #pragma unroll
    for (int j = 0; j < 8; j++) o[j] = f2bf(accB[j] * invB);
    *reinterpret_cast<u16x8*>(outB + (size_t)d * 256 + l5 * 8) = o;
  }
}

// ---- stacked-K GEMM v6: C = [A0|A1](bf16 50000x512) @ WT^T + deg-masked biases.
// 64 rows x 256 cols per block, grid 782. K in 8 chunks of 64.
// A: 4-deep LDS ring via global_load_lds (16B), prefetch distance 3, raw s_barrier,
// uniform vmcnt(4) -- never drains the DMA queue. B issued FIRST each iteration so
// compiler B-waits (in-order vmcnt retirement) retire stage(ck) but keep stage(ck+3)
// in flight. XOR-swizzled A staging/reads (T2 + rule 21, proven in round 4).
// MODE 0: leaky_relu + bf16. MODE 1: f32.
template<int MODE>
__global__ __launch_bounds__(256, 3) void gemm512(
    const unsigned short* __restrict__ A0, const unsigned short* __restrict__ A1,
    const unsigned short* __restrict__ WT,
    const float* __restrict__ bA, const float* __restrict__ bB,
    const int* __restrict__ S, int etA, int etB,
    void* __restrict__ outp, int M)
{
  __shared__ unsigned short abuf[4][64 * 64];   // 4-deep ring, 8KB each
  int tid = threadIdx.x;
  int m0 = blockIdx.x * 64;
  int wave = tid >> 6, lane = tid & 63;
  int wr = wave >> 1, wc = wave & 1;
  int lrow = lane & 15, kgrp = lane >> 4;

  // staging geometry: per instr, wave covers 8 rows x 128B fully coalesced;
  // LDS dest = wave-uniform base + lane*16 (linear), source col inverse-swizzled.
  int ld_wbase = wave << 10;
  int ld_row0 = tid >> 3;                                   // 0..31 (iss 1 adds 32)
  int ld_kb0 = ((tid & 7) << 4) ^ ((ld_row0 & 7) << 4);

  f32x4 acc[2][8];
  #pragma unroll
  for (int a = 0; a < 2; a++)
    #pragma unroll
    for (int b = 0; b < 8; b++) acc[a][b] = (f32x4){0.f, 0.f, 0.f, 0.f};

  // B row pointers (WT row stride = 512 bf16), kgrp folded in
  const unsigned short* wb[8];
  #pragma unroll
  for (int nb = 0; nb < 8; nb++)
    wb[nb] = WT + (size_t)(128 * wc + 16 * nb + lrow) * 512 + kgrp * 8;

  auto stage = [&](int ck) {
    const unsigned short* Asrc = (ck < 4) ? A0 : A1;
    int ckk = ck & 3;
    char* dst = (char*)&abuf[ck & 3][0] + ld_wbase;
    #pragma unroll
    for (int iss = 0; iss < 2; iss++) {
      const char* src = (const char*)Asrc +
          (size_t)(m0 + iss * 32 + ld_row0) * 512 + ckk * 128 + ld_kb0;
      __builtin_amdgcn_global_load_lds(
          (const AS1 unsigned int*)(const void*)src,
          (AS3 unsigned int*)(void*)(dst + iss * 4096), 16, 0, 0);
    }
  };

  stage(0); stage(1); stage(2);       // 6 DMA loads in flight

  int r0 = 32 * wr + lrow;
  int r1 = r0 + 16;
  int sw0 = (r0 & 7) << 4;

  #pragma unroll
  for (int ck = 0; ck < 8; ck++) {
    // own stage(ck) guaranteed retired: iter 0 by this wait, later iters by the
    // previous compute's B-operand waits (B(ck-1) is newer in the vmcnt queue).
    asm volatile("s_waitcnt vmcnt(4)" ::: "memory");
    __builtin_amdgcn_s_barrier();     // all waves' stage(ck) DMA now visible

    // B loads FIRST (so MFMA B-waits don't retire the stage issued below)
    bf16x8 breg[2][8];
    #pragma unroll
    for (int ks = 0; ks < 2; ks++)
      #pragma unroll
      for (int nb = 0; nb < 8; nb++)
        breg[ks][nb] = *reinterpret_cast<const bf16x8*>(wb[nb] + ck * 64 + ks * 32);
    __builtin_amdgcn_sched_barrier(0);  // pin B-before-stage queue order
    if (ck < 5) stage(ck + 3);

    const char* bufp = (const char*)&abuf[ck & 3][0];
    #pragma unroll
    for (int ks = 0; ks < 2; ks++) {
      int kb = ks * 64 + kgrp * 16;
      bf16x8 a0 = *reinterpret_cast<const bf16x8*>(bufp + r0 * 128 + (kb ^ sw0));
      bf16x8 a1 = *reinterpret_cast<const bf16x8*>(bufp + r1 * 128 + (kb ^ sw0));
      #pragma unroll
      for (int nb = 0; nb < 8; nb++) {
        acc[0][nb] = __builtin_amdgcn_mfma_f32_16x16x32_bf16(a0, breg[ks][nb], acc[0][nb], 0, 0, 0);
        acc[1][nb] = __builtin_amdgcn_mfma_f32_16x16x32_bf16(a1, breg[ks][nb], acc[1][nb], 0, 0, 0);
      }
    }
  }

  // C/D layout: col = lane&15, row = (lane>>4)*4 + reg  [verified m89/m91]
  #pragma unroll
  for (int mb = 0; mb < 2; mb++) {
    #pragma unroll
    for (int r = 0; r < 4; r++) {
      int row = m0 + 32 * wr + 16 * mb + kgrp * 4 + r;
      if (row >= M) continue;
      int gA = etA * NNODE + row, gB = etB * NNODE + row;
      bool hA = S[gA + 1] > S[gA];   // deg>0: bias enters only via messages
      bool hB = S[gB + 1] > S[gB];
      #pragma unroll
      for (int nb = 0; nb < 8; nb++) {
        int col = 128 * wc + 16 * nb + lrow;
        float bias = (hA ? bA[col] : 0.f) + (hB ? bB[col] : 0.f);
        float v = acc[mb][nb][r] + bias;
        if (MODE == 0) {
          v = (v > 0.f) ? v : 0.01f * v;
          ((unsigned short*)outp)[(size_t)row * 256 + col] = f2bf(v);
        } else {
          ((float*)outp)[(size_t)row * 256 + col] = v;
        }
      }
    }
  }
}

extern "C" void kernel_launch(void* const* d_in, const int* in_sizes, int n_in,
                              void* d_out, int out_size, void* d_ws, size_t ws_size,
                              hipStream_t stream) {
  (void)in_sizes; (void)n_in;
  const float* chem = (const float*)d_in[0];
  const float* gene = (const float*)d_in[1];
  const float *W1[4], *B1[4], *W2[4], *B2[4];
  const int *SRC[4], *DST[4];
  // etype order: 0=ch2ge, 1=ge2ch, 2=ch2ch, 3=ge2ge
  for (int t = 0; t < 4; t++) {
    W1[t]  = (const float*)d_in[2 + 6 * t];
    B1[t]  = (const float*)d_in[3 + 6 * t];
    W2[t]  = (const float*)d_in[4 + 6 * t];
    B2[t]  = (const float*)d_in[5 + 6 * t];
    SRC[t] = (const int*)d_in[6 + 6 * t];
    DST[t] = (const int*)d_in[7 + 6 * t];
  }

  size_t off_b = 0;
  auto carve = [&](size_t bytes) -> void* {
    void* p = (char*)d_ws + off_b;
    off_b += (bytes + 255) & ~(size_t)255;
    return p;
  };
  const size_t FEAT_B = (size_t)NNODE * DIM * 2;  // 25.6 MB bf16
  unsigned short* xb_chem = (unsigned short*)carve(FEAT_B);
  unsigned short* xb_gene = (unsigned short*)carve(FEAT_B);
  unsigned short* h1_chem = (unsigned short*)carve(FEAT_B);
  unsigned short* h1_gene = (unsigned short*)carve(FEAT_B);
  unsigned short* aggA    = (unsigned short*)carve(FEAT_B);  // pairs+scan matrix aliased here
  unsigned short* aggB    = (unsigned short*)carve(FEAT_B);
  int* S    = (int*)carve(((size_t)NTOT + 1) * 4);
  int* srcs = (int*)carve((size_t)NET * EDGES * 4);
  unsigned short* WTc1 = (unsigned short*)carve((size_t)256 * 512 * 2);
  unsigned short* WTg1 = (unsigned short*)carve((size_t)256 * 512 * 2);
  unsigned short* WTc2 = (unsigned short*)carve((size_t)256 * 512 * 2);
  // aliases inside aggA (dead until after CSR build):
  unsigned int* pairs = (unsigned int*)aggA;                         // 6.4 MB
  int* cntoff = (int*)((char*)aggA + 6400000);                       // NSCAN+1 ints, in-place scan
  int* bsum   = cntoff + (NSCAN + 1);                                // 128 ints

  if (off_b > ws_size) {
    fill_f32<<<(out_size + 255) / 256, 256, 0, stream>>>((float*)d_out, (float)(ws_size >> 20), out_size);
    return;
  }

  int n4 = NNODE * DIM / 4;
  conv_f32_bf16<<<(n4 + 255) / 256, 256, 0, stream>>>(chem, xb_chem, n4);
  conv_f32_bf16<<<(n4 + 255) / 256, 256, 0, stream>>>(gene, xb_gene, n4);
  // stacked WTs: c1=(W1[1],W1[2])  g1=(W1[0],W1[3])  c2=(W2[1],W2[2])
  conv_wT3<<<dim3(256, 3), 256, 0, stream>>>(W1[1], W1[2], W1[0], W1[3], W2[1], W2[2],
                                             WTc1, WTg1, WTc2);

  // ---- multi-split CSR build ----
  dim3 cgrid(CPE, 4);
  hist_ms<<<cgrid, 256, 0, stream>>>(DST[0], DST[1], DST[2], DST[3], cntoff);
  int nb1 = (NSCAN + 4095) / 4096;   // 75
  scan_p1<<<nb1, 256, 0, stream>>>(cntoff, bsum, NSCAN);
  scan_p2<<<1, 128, 0, stream>>>(bsum, nb1, cntoff, NSCAN, S);
  scan_p3<<<nb1, 256, 0, stream>>>(cntoff, bsum, NSCAN);
  scatter_ms<<<cgrid, 256, 0, stream>>>(SRC[0], SRC[1], SRC[2], SRC[3],
                                        DST[0], DST[1], DST[2], DST[3], cntoff, pairs);
  bucket_final<<<NBUCK, 256, 0, stream>>>(cntoff, pairs, S, srcs);

  dim3 ggrid2((NNODE + 63) / 64);   // 782 blocks, full-N per block
  int nagg = NNODE / 4;             // 12500 blocks x 4 waves
  // ---- layer 1, dt=chemical: et1 (src gene) + et2 (src chem)
  agg_pair<<<nagg, 256, 0, stream>>>(S, srcs, xb_gene, 1, aggA, xb_chem, 2, aggB);
  gemm512<0><<<ggrid2, 256, 0, stream>>>(aggA, aggB, WTc1, B1[1], B1[2], S, 1, 2, h1_chem, NNODE);
  // ---- layer 1, dt=gene: et0 (src chem) + et3 (src gene)
  agg_pair<<<nagg, 256, 0, stream>>>(S, srcs, xb_chem, 0, aggA, xb_gene, 3, aggB);
  gemm512<0><<<ggrid2, 256, 0, stream>>>(aggA, aggB, WTg1, B1[0], B1[3], S, 0, 3, h1_gene, NNODE);
  // ---- layer 2, dt=chemical only: et1 (src h1_gene) + et2 (src h1_chem)
  agg_pair<<<nagg, 256, 0, stream>>>(S, srcs, h1_gene, 1, aggA, h1_chem, 2, aggB);
  gemm512<1><<<ggrid2, 256, 0, stream>>>(aggA, aggB, WTc2, B2[1], B2[2], S, 1, 2, d_out, NNODE);
}

// Round 7
// 435.055 us; speedup vs baseline: 1.3092x; 1.3092x over previous
//
#include <hip/hip_runtime.h>
#include <hip/hip_bf16.h>

#define NNODE 50000
#define DIM   256
#define EDGES 400000
#define NET   4
#define NTOT  (NET * NNODE)          // 200000
#define BSH   7
#define NBUCK ((NTOT + 127) >> BSH)  // 1563
#define EPB2  8192                   // edges per chunk
#define CPE   49                     // chunks per etype (49*8192 >= 400000)
#define NBLKT (CPE * NET)            // 196 chunk-blocks total
#define NSCAN (NBUCK * NBLKT)        // 306348

#define AS1 __attribute__((address_space(1)))
#define AS3 __attribute__((address_space(3)))

typedef __attribute__((ext_vector_type(8))) __bf16 bf16x8;
typedef __attribute__((ext_vector_type(4))) float f32x4;
typedef __attribute__((ext_vector_type(4))) unsigned short u16x4;
typedef __attribute__((ext_vector_type(8))) unsigned short u16x8;

__device__ __forceinline__ float bf2f(unsigned short u) {
  unsigned int x = ((unsigned int)u) << 16;
  return __builtin_bit_cast(float, x);
}
__device__ __forceinline__ unsigned short f2bf(float f) {
  __hip_bfloat16 h = __float2bfloat16(f);   // RTNE
  return __builtin_bit_cast(unsigned short, h);
}

__global__ void conv_f32_bf16(const float* __restrict__ in, unsigned short* __restrict__ out, int n4) {
  int i = blockIdx.x * blockDim.x + threadIdx.x;
  if (i >= n4) return;
  f32x4 v = reinterpret_cast<const f32x4*>(in)[i];
  u16x4 o;
  o[0] = f2bf(v[0]); o[1] = f2bf(v[1]); o[2] = f2bf(v[2]); o[3] = f2bf(v[3]);
  reinterpret_cast<u16x4*>(out)[i] = o;
}

// Build 3 stacked-K transposed weight matrices: T[n][k] with k<256 from A, k>=256 from B.
__global__ void conv_wT3(const float* __restrict__ a0, const float* __restrict__ b0,
                         const float* __restrict__ a1, const float* __restrict__ b1,
                         const float* __restrict__ a2, const float* __restrict__ b2,
                         unsigned short* __restrict__ t0, unsigned short* __restrict__ t1,
                         unsigned short* __restrict__ t2) {
  int m = blockIdx.y;
  const float* A = (m == 0) ? a0 : (m == 1) ? a1 : a2;
  const float* B = (m == 0) ? b0 : (m == 1) ? b1 : b2;
  unsigned short* T = (m == 0) ? t0 : (m == 1) ? t1 : t2;
  int n = blockIdx.x, k = threadIdx.x;   // 256 threads
  T[n * 512 + k]       = f2bf(A[k * 256 + n]);
  T[n * 512 + 256 + k] = f2bf(B[k * 256 + n]);
}

__global__ void fill_f32(float* __restrict__ p, float v, int n) {
  int i = blockIdx.x * blockDim.x + threadIdx.x;
  if (i < n) p[i] = v;
}

// ---- multi-split CSR build: no per-edge global atomics ----
__global__ void hist_ms(const int* __restrict__ d0, const int* __restrict__ d1,
                        const int* __restrict__ d2, const int* __restrict__ d3,
                        int* __restrict__ cnt) {
  __shared__ int h[NBUCK];
  for (int i = threadIdx.x; i < NBUCK; i += 256) h[i] = 0;
  __syncthreads();
  int t = blockIdx.y, cx = blockIdx.x;
  const int* dp = (t == 0) ? d0 : (t == 1) ? d1 : (t == 2) ? d2 : d3;
  int base = cx * EPB2;
  int lim = base + EPB2; if (lim > EDGES) lim = EDGES;
  for (int i = base + threadIdx.x; i < lim; i += 256)
    atomicAdd(&h[(t * NNODE + dp[i]) >> BSH], 1);
  __syncthreads();
  int blk = t * CPE + cx;
  for (int i = threadIdx.x; i < NBUCK; i += 256)
    cnt[i * NBLKT + blk] = h[i];
}

__global__ void scan_p1(const int* __restrict__ data, int* __restrict__ bsum, int n) {
  __shared__ int red[256];
  int base = blockIdx.x * 4096;
  int s = 0;
  #pragma unroll
  for (int j = 0; j < 16; j++) {
    int idx = base + j * 256 + threadIdx.x;
    s += (idx < n) ? data[idx] : 0;
  }
  red[threadIdx.x] = s;
  __syncthreads();
  for (int o = 128; o > 0; o >>= 1) {
    if (threadIdx.x < o) red[threadIdx.x] += red[threadIdx.x + o];
    __syncthreads();
  }
  if (threadIdx.x == 0) bsum[blockIdx.x] = red[0];
}

__global__ void scan_p2(int* __restrict__ bsum, int nb, int* __restrict__ off, int nscan,
                        int* __restrict__ S) {
  __shared__ int sh[128];
  int tid = threadIdx.x;
  int v = (tid < nb) ? bsum[tid] : 0;
  sh[tid] = v;
  __syncthreads();
  for (int o = 1; o < 128; o <<= 1) {
    int a = (tid >= o) ? sh[tid - o] : 0;
    __syncthreads();
    sh[tid] += a;
    __syncthreads();
  }
  if (tid < nb) bsum[tid] = sh[tid] - v;   // exclusive block bases
  if (tid == 0) { off[nscan] = sh[127]; S[NTOT] = sh[127]; }
}

__global__ void scan_p3(int* __restrict__ data, const int* __restrict__ bsum, int n) {
  __shared__ int sh[256];
  int tid = threadIdx.x;
  int base = blockIdx.x * 4096 + tid * 16;
  int vals[16];
  int s = 0;
  #pragma unroll
  for (int j = 0; j < 16; j++) {
    vals[j] = (base + j < n) ? data[base + j] : 0;
    s += vals[j];
  }
  sh[tid] = s;
  __syncthreads();
  for (int o = 1; o < 256; o <<= 1) {
    int a = (tid >= o) ? sh[tid - o] : 0;
    __syncthreads();
    sh[tid] += a;
    __syncthreads();
  }
  int run = bsum[blockIdx.x] + sh[tid] - s;
  #pragma unroll
  for (int j = 0; j < 16; j++) {
    if (base + j < n) { data[base + j] = run; run += vals[j]; }
  }
}

__global__ void scatter_ms(const int* __restrict__ s0, const int* __restrict__ s1,
                           const int* __restrict__ s2, const int* __restrict__ s3,
                           const int* __restrict__ d0, const int* __restrict__ d1,
                           const int* __restrict__ d2, const int* __restrict__ d3,
                           const int* __restrict__ off, unsigned int* __restrict__ pairs) {
  __shared__ int cur[NBUCK];
  int t = blockIdx.y, cx = blockIdx.x;
  int blk = t * CPE + cx;
  for (int i = threadIdx.x; i < NBUCK; i += 256)
    cur[i] = off[i * NBLKT + blk];
  __syncthreads();
  const int* sp = (t == 0) ? s0 : (t == 1) ? s1 : (t == 2) ? s2 : s3;
  const int* dp = (t == 0) ? d0 : (t == 1) ? d1 : (t == 2) ? d2 : d3;
  int base = cx * EPB2;
  int lim = base + EPB2; if (lim > EDGES) lim = EDGES;
  for (int i = base + threadIdx.x; i < lim; i += 256) {
    int key = t * NNODE + dp[i];
    int slot = atomicAdd(&cur[key >> BSH], 1);
    pairs[slot] = ((unsigned int)(key & 127) << 16) | (unsigned int)sp[i];
  }
}

__global__ void bucket_final(const int* __restrict__ off, const unsigned int* __restrict__ pairs,
                             int* __restrict__ S, int* __restrict__ srcs) {
  __shared__ int lcnt[128];
  __shared__ int loff[128];
  int b = blockIdx.x;
  int tid = threadIdx.x;
  int beg = off[b * NBLKT], end = off[(b + 1) * NBLKT];
  if (tid < 128) lcnt[tid] = 0;
  __syncthreads();
  for (int e = beg + tid; e < end; e += 256)
    atomicAdd(&lcnt[pairs[e] >> 16], 1);
  __syncthreads();
  int c = (tid < 128) ? lcnt[tid] : 0;
  if (tid < 128) loff[tid] = c;
  __syncthreads();
  for (int o = 1; o < 128; o <<= 1) {
    int a = (tid < 128 && tid >= o) ? loff[tid - o] : 0;
    __syncthreads();
    if (tid < 128) loff[tid] += a;
    __syncthreads();
  }
  if (tid < 128) {
    int ex = loff[tid] - c;
    int key = (b << BSH) + tid;
    if (key < NTOT) S[key] = beg + ex;
    lcnt[tid] = ex;                   // running cursor
  }
  __syncthreads();
  for (int e = beg + tid; e < end; e += 256) {
    unsigned int p = pairs[e];
    int lk = p >> 16;
    int slot = beg + atomicAdd(&lcnt[lk], 1);
    srcs[slot] = (int)(p & 0xFFFFu);
  }
}

// ---- aggregation: mean of src features per (etype, dst). Two etypes fused.
__device__ __forceinline__ void agg_loop(const int* __restrict__ srcs, int e0, int e1,
                                         int half, int l5,
                                         const unsigned short* __restrict__ feat, float* acc) {
  int e = e0 + half;
  u16x8 v = {};
  if (e < e1) v = *reinterpret_cast<const u16x8*>(feat + (size_t)srcs[e] * 256 + l5 * 8);
  while (e < e1) {
    u16x8 cur = v;
    e += 2;
    if (e < e1) v = *reinterpret_cast<const u16x8*>(feat + (size_t)srcs[e] * 256 + l5 * 8);
    #pragma unroll
    for (int j = 0; j < 8; j++) acc[j] += bf2f(cur[j]);
  }
}

__global__ __launch_bounds__(256) void agg_pair(
    const int* __restrict__ S, const int* __restrict__ srcs,
    const unsigned short* __restrict__ featA, int etA, unsigned short* __restrict__ outA,
    const unsigned short* __restrict__ featB, int etB, unsigned short* __restrict__ outB)
{
  int d = blockIdx.x * 4 + (threadIdx.x >> 6);
  int lane = threadIdx.x & 63;
  int half = lane >> 5, l5 = lane & 31;

  float accA[8] = {0,0,0,0,0,0,0,0}, accB[8] = {0,0,0,0,0,0,0,0};
  int gA = etA * NNODE + d;
  int a0 = S[gA], a1 = S[gA + 1];
  agg_loop(srcs, a0, a1, half, l5, featA, accA);
  int gB = etB * NNODE + d;
  int b0 = S[gB], b1 = S[gB + 1];
  agg_loop(srcs, b0, b1, half, l5, featB, accB);

  #pragma unroll
  for (int j = 0; j < 8; j++) {
    accA[j] += __shfl_xor(accA[j], 32);
    accB[j] += __shfl_xor(accB[j], 32);
  }
  float dA = (float)(a1 - a0); if (dA < 1.f) dA = 1.f;
  float dB = (float)(b1 - b0); if (dB < 1.f) dB = 1.f;
  float invA = 1.f / dA, invB = 1.f / dB;

  u16x8 o;
  if (half == 0) {
    #pragma unroll
    for (int j = 0; j < 8; j++) o[j] = f2bf(accA[j] * invA);
    *reinterpret_cast<u16x8*>(outA + (size_t)d * 256 + l5 * 8) = o;
  } else {
    #pragma unroll
    for (int j = 0; j < 8; j++) o[j] = f2bf(accB[j] * invB);
    *reinterpret_cast<u16x8*>(outB + (size_t)d * 256 + l5 * 8) = o;
  }
}

// ---- stacked-K GEMM v7: C = [A0|A1](bf16 50000x512) @ WT^T + deg-masked biases.
// Key change vs v6: NO per-fragment global gathers. Both A and B chunks are staged
// into LDS via global_load_lds from PERFECTLY COALESCED sources (1 cacheline per
// row), all fragment reads are ds_read_b128 with a 2-way (free) bank swizzle
// slot = kgrp ^ ((row>>1)&3), inverse-applied at the global source (rule 21).
// Tile 128 rows x 256 cols, 4 waves x (64r x 128c), acc[4][8]. K-chunk = 32,
// double-buffered (48KB), v6 queue discipline: stage(ck+1) -> vmcnt(6) ->
// raw barrier -> compute(ck) -> barrier. MODE 0: leaky_relu+bf16. MODE 1: f32.
template<int MODE>
__global__ __launch_bounds__(256, 2) void gemm512(
    const unsigned short* __restrict__ A0, const unsigned short* __restrict__ A1,
    const unsigned short* __restrict__ WT,
    const float* __restrict__ bA, const float* __restrict__ bB,
    const int* __restrict__ S, int etA, int etB,
    void* __restrict__ outp, int M)
{
  __shared__ char lds[2 * 24576];     // per half: A chunk 8KB + B chunk 16KB
  int tid = threadIdx.x;
  int m0 = blockIdx.x * 128;
  int wave = tid >> 6, lane = tid & 63;
  int wr = wave >> 1, wc = wave & 1;
  int lrow = lane & 15, kgrp = lane >> 4;

  f32x4 acc[4][8];
  #pragma unroll
  for (int a = 0; a < 4; a++)
    #pragma unroll
    for (int b = 0; b < 8; b++) acc[a][b] = (f32x4){0.f, 0.f, 0.f, 0.f};

  // precomputed swizzled fragment byte offsets within a chunk-half
  int a_off[4], b_off[8];
  #pragma unroll
  for (int mb = 0; mb < 4; mb++) {
    int row = 64 * wr + 16 * mb + lrow;
    a_off[mb] = row * 64 + ((kgrp ^ ((row >> 1) & 3)) << 4);
  }
  #pragma unroll
  for (int nb = 0; nb < 8; nb++) {
    int row = 128 * wc + 16 * nb + lrow;
    b_off[nb] = 8192 + row * 64 + ((kgrp ^ ((row >> 1) & 3)) << 4);
  }

  int srow = tid >> 2;        // staging: 4 threads/row, 16B each
  int sseg = tid & 3;

  auto stage = [&](int ck) {
    char* half = lds + (ck & 1) * 24576;
    // B chunk: 256 rows x 64B (one cacheline per WT row), 4 issues
    const char* wsrc = (const char*)WT + ck * 64;
    #pragma unroll
    for (int iss = 0; iss < 4; iss++) {
      int row = iss * 64 + srow;
      int g = (row >> 1) & 3;
      const char* src = wsrc + (size_t)row * 1024 + ((sseg ^ g) << 4);
      __builtin_amdgcn_global_load_lds(
          (const AS1 unsigned int*)(const void*)src,
          (AS3 unsigned int*)(void*)(half + 8192 + iss * 4096 + tid * 16), 16, 0, 0);
    }
    // A chunk: 128 rows x 64B (contiguous 64B per row), 2 issues
    const char* asrc = (const char*)((ck < 8) ? A0 : A1) + (ck & 7) * 64;
    #pragma unroll
    for (int iss = 0; iss < 2; iss++) {
      int row = iss * 64 + srow;
      int g = (row >> 1) & 3;
      const char* src = asrc + (size_t)(m0 + row) * 512 + ((sseg ^ g) << 4);
      __builtin_amdgcn_global_load_lds(
          (const AS1 unsigned int*)(const void*)src,
          (AS3 unsigned int*)(void*)(half + iss * 4096 + tid * 16), 16, 0, 0);
    }
  };

  auto compute = [&](int ck) {
    const char* half = lds + (ck & 1) * 24576;
    bf16x8 a[4];
    #pragma unroll
    for (int mb = 0; mb < 4; mb++)
      a[mb] = *reinterpret_cast<const bf16x8*>(half + a_off[mb]);
    #pragma unroll
    for (int nb = 0; nb < 8; nb++) {
      bf16x8 b = *reinterpret_cast<const bf16x8*>(half + b_off[nb]);
      #pragma unroll
      for (int mb = 0; mb < 4; mb++)
        acc[mb][nb] = __builtin_amdgcn_mfma_f32_16x16x32_bf16(a[mb], b, acc[mb][nb], 0, 0, 0);
    }
  };

  stage(0);
  for (int ck = 0; ck < 15; ck++) {
    stage(ck + 1);                                   // queue: 6 old + 6 new
    asm volatile("s_waitcnt vmcnt(6)" ::: "memory"); // retire stage(ck) only
    asm volatile("s_barrier" ::: "memory");          // stage(ck) visible to all
    compute(ck);
    asm volatile("s_barrier" ::: "memory");          // all done reading buf[ck&1]
  }
  asm volatile("s_waitcnt vmcnt(0)" ::: "memory");
  asm volatile("s_barrier" ::: "memory");
  compute(15);

  // C/D layout: col = lane&15, row = (lane>>4)*4 + reg  [verified m89/m91]
  #pragma unroll
  for (int mb = 0; mb < 4; mb++) {
    #pragma unroll
    for (int r = 0; r < 4; r++) {
      int row = m0 + 64 * wr + 16 * mb + kgrp * 4 + r;
      if (row >= M) continue;
      int gA = etA * NNODE + row, gB = etB * NNODE + row;
      bool hA = S[gA + 1] > S[gA];   // deg>0: bias enters only via messages
      bool hB = S[gB + 1] > S[gB];
      #pragma unroll
      for (int nb = 0; nb < 8; nb++) {
        int col = 128 * wc + 16 * nb + lrow;
        float bias = (hA ? bA[col] : 0.f) + (hB ? bB[col] : 0.f);
        float v = acc[mb][nb][r] + bias;
        if (MODE == 0) {
          v = (v > 0.f) ? v : 0.01f * v;
          ((unsigned short*)outp)[(size_t)row * 256 + col] = f2bf(v);
        } else {
          ((float*)outp)[(size_t)row * 256 + col] = v;
        }
      }
    }
  }
}

extern "C" void kernel_launch(void* const* d_in, const int* in_sizes, int n_in,
                              void* d_out, int out_size, void* d_ws, size_t ws_size,
                              hipStream_t stream) {
  (void)in_sizes; (void)n_in;
  const float* chem = (const float*)d_in[0];
  const float* gene = (const float*)d_in[1];
  const float *W1[4], *B1[4], *W2[4], *B2[4];
  const int *SRC[4], *DST[4];
  // etype order: 0=ch2ge, 1=ge2ch, 2=ch2ch, 3=ge2ge
  for (int t = 0; t < 4; t++) {
    W1[t]  = (const float*)d_in[2 + 6 * t];
    B1[t]  = (const float*)d_in[3 + 6 * t];
    W2[t]  = (const float*)d_in[4 + 6 * t];
    B2[t]  = (const float*)d_in[5 + 6 * t];
    SRC[t] = (const int*)d_in[6 + 6 * t];
    DST[t] = (const int*)d_in[7 + 6 * t];
  }

  size_t off_b = 0;
  auto carve = [&](size_t bytes) -> void* {
    void* p = (char*)d_ws + off_b;
    off_b += (bytes + 255) & ~(size_t)255;
    return p;
  };
  const size_t FEAT_B = (size_t)NNODE * DIM * 2;  // 25.6 MB bf16
  unsigned short* xb_chem = (unsigned short*)carve(FEAT_B);
  unsigned short* xb_gene = (unsigned short*)carve(FEAT_B);
  unsigned short* h1_chem = (unsigned short*)carve(FEAT_B);
  unsigned short* h1_gene = (unsigned short*)carve(FEAT_B);
  unsigned short* aggA    = (unsigned short*)carve(FEAT_B);  // pairs+scan matrix aliased here
  unsigned short* aggB    = (unsigned short*)carve(FEAT_B);
  int* S    = (int*)carve(((size_t)NTOT + 1) * 4);
  int* srcs = (int*)carve((size_t)NET * EDGES * 4);
  unsigned short* WTc1 = (unsigned short*)carve((size_t)256 * 512 * 2);
  unsigned short* WTg1 = (unsigned short*)carve((size_t)256 * 512 * 2);
  unsigned short* WTc2 = (unsigned short*)carve((size_t)256 * 512 * 2);
  // aliases inside aggA (dead until after CSR build):
  unsigned int* pairs = (unsigned int*)aggA;                         // 6.4 MB
  int* cntoff = (int*)((char*)aggA + 6400000);                       // NSCAN+1 ints, in-place scan
  int* bsum   = cntoff + (NSCAN + 1);                                // 128 ints

  if (off_b > ws_size) {
    fill_f32<<<(out_size + 255) / 256, 256, 0, stream>>>((float*)d_out, (float)(ws_size >> 20), out_size);
    return;
  }

  int n4 = NNODE * DIM / 4;
  conv_f32_bf16<<<(n4 + 255) / 256, 256, 0, stream>>>(chem, xb_chem, n4);
  conv_f32_bf16<<<(n4 + 255) / 256, 256, 0, stream>>>(gene, xb_gene, n4);
  // stacked WTs: c1=(W1[1],W1[2])  g1=(W1[0],W1[3])  c2=(W2[1],W2[2])
  conv_wT3<<<dim3(256, 3), 256, 0, stream>>>(W1[1], W1[2], W1[0], W1[3], W2[1], W2[2],
                                             WTc1, WTg1, WTc2);

  // ---- multi-split CSR build ----
  dim3 cgrid(CPE, 4);
  hist_ms<<<cgrid, 256, 0, stream>>>(DST[0], DST[1], DST[2], DST[3], cntoff);
  int nb1 = (NSCAN + 4095) / 4096;   // 75
  scan_p1<<<nb1, 256, 0, stream>>>(cntoff, bsum, NSCAN);
  scan_p2<<<1, 128, 0, stream>>>(bsum, nb1, cntoff, NSCAN, S);
  scan_p3<<<nb1, 256, 0, stream>>>(cntoff, bsum, NSCAN);
  scatter_ms<<<cgrid, 256, 0, stream>>>(SRC[0], SRC[1], SRC[2], SRC[3],
                                        DST[0], DST[1], DST[2], DST[3], cntoff, pairs);
  bucket_final<<<NBUCK, 256, 0, stream>>>(cntoff, pairs, S, srcs);

  dim3 ggrid2((NNODE + 127) / 128);   // 391 blocks, full-N per block
  int nagg = NNODE / 4;               // 12500 blocks x 4 waves
  // ---- layer 1, dt=chemical: et1 (src gene) + et2 (src chem)
  agg_pair<<<nagg, 256, 0, stream>>>(S, srcs, xb_gene, 1, aggA, xb_chem, 2, aggB);
  gemm512<0><<<ggrid2, 256, 0, stream>>>(aggA, aggB, WTc1, B1[1], B1[2], S, 1, 2, h1_chem, NNODE);
  // ---- layer 1, dt=gene: et0 (src chem) + et3 (src gene)
  agg_pair<<<nagg, 256, 0, stream>>>(S, srcs, xb_chem, 0, aggA, xb_gene, 3, aggB);
  gemm512<0><<<ggrid2, 256, 0, stream>>>(aggA, aggB, WTg1, B1[0], B1[3], S, 0, 3, h1_gene, NNODE);
  // ---- layer 2, dt=chemical only: et1 (src h1_gene) + et2 (src h1_chem)
  agg_pair<<<nagg, 256, 0, stream>>>(S, srcs, h1_gene, 1, aggA, h1_chem, 2, aggB);
  gemm512<1><<<ggrid2, 256, 0, stream>>>(aggA, aggB, WTc2, B2[1], B2[2], S, 1, 2, d_out, NNODE);
}

// Round 8
// 421.090 us; speedup vs baseline: 1.3526x; 1.0332x over previous
//
#include <hip/hip_runtime.h>
#include <hip/hip_bf16.h>

#define NNODE 50000
#define DIM   256
#define EDGES 400000
#define NET   4
#define NTOT  (NET * NNODE)          // 200000
#define BSH   7
#define NBUCK ((NTOT + 127) >> BSH)  // 1563
#define EPB2  8192                   // edges per chunk
#define CPE   49                     // chunks per etype (49*8192 >= 400000)
#define NBLKT (CPE * NET)            // 196 chunk-blocks total
#define NSCAN (NBUCK * NBLKT)        // 306348

#define AS1 __attribute__((address_space(1)))
#define AS3 __attribute__((address_space(3)))

typedef __attribute__((ext_vector_type(8))) __bf16 bf16x8;
typedef __attribute__((ext_vector_type(4))) float f32x4;
typedef __attribute__((ext_vector_type(4))) unsigned short u16x4;
typedef __attribute__((ext_vector_type(8))) unsigned short u16x8;

__device__ __forceinline__ float bf2f(unsigned short u) {
  unsigned int x = ((unsigned int)u) << 16;
  return __builtin_bit_cast(float, x);
}
__device__ __forceinline__ unsigned short f2bf(float f) {
  __hip_bfloat16 h = __float2bfloat16(f);   // RTNE
  return __builtin_bit_cast(unsigned short, h);
}

__global__ void conv_f32_bf16(const float* __restrict__ in, unsigned short* __restrict__ out, int n4) {
  int i = blockIdx.x * blockDim.x + threadIdx.x;
  if (i >= n4) return;
  f32x4 v = reinterpret_cast<const f32x4*>(in)[i];
  u16x4 o;
  o[0] = f2bf(v[0]); o[1] = f2bf(v[1]); o[2] = f2bf(v[2]); o[3] = f2bf(v[3]);
  reinterpret_cast<u16x4*>(out)[i] = o;
}

// Build 3 stacked-K transposed weight matrices: T[n][k] with k<256 from A, k>=256 from B.
__global__ void conv_wT3(const float* __restrict__ a0, const float* __restrict__ b0,
                         const float* __restrict__ a1, const float* __restrict__ b1,
                         const float* __restrict__ a2, const float* __restrict__ b2,
                         unsigned short* __restrict__ t0, unsigned short* __restrict__ t1,
                         unsigned short* __restrict__ t2) {
  int m = blockIdx.y;
  const float* A = (m == 0) ? a0 : (m == 1) ? a1 : a2;
  const float* B = (m == 0) ? b0 : (m == 1) ? b1 : b2;
  unsigned short* T = (m == 0) ? t0 : (m == 1) ? t1 : t2;
  int n = blockIdx.x, k = threadIdx.x;   // 256 threads
  T[n * 512 + k]       = f2bf(A[k * 256 + n]);
  T[n * 512 + 256 + k] = f2bf(B[k * 256 + n]);
}

__global__ void fill_f32(float* __restrict__ p, float v, int n) {
  int i = blockIdx.x * blockDim.x + threadIdx.x;
  if (i < n) p[i] = v;
}

// ---- multi-split CSR build: no per-edge global atomics ----
__global__ void hist_ms(const int* __restrict__ d0, const int* __restrict__ d1,
                        const int* __restrict__ d2, const int* __restrict__ d3,
                        int* __restrict__ cnt) {
  __shared__ int h[NBUCK];
  for (int i = threadIdx.x; i < NBUCK; i += 256) h[i] = 0;
  __syncthreads();
  int t = blockIdx.y, cx = blockIdx.x;
  const int* dp = (t == 0) ? d0 : (t == 1) ? d1 : (t == 2) ? d2 : d3;
  int base = cx * EPB2;
  int lim = base + EPB2; if (lim > EDGES) lim = EDGES;
  for (int i = base + threadIdx.x; i < lim; i += 256)
    atomicAdd(&h[(t * NNODE + dp[i]) >> BSH], 1);
  __syncthreads();
  int blk = t * CPE + cx;
  for (int i = threadIdx.x; i < NBUCK; i += 256)
    cnt[i * NBLKT + blk] = h[i];
}

__global__ void scan_p1(const int* __restrict__ data, int* __restrict__ bsum, int n) {
  __shared__ int red[256];
  int base = blockIdx.x * 4096;
  int s = 0;
  #pragma unroll
  for (int j = 0; j < 16; j++) {
    int idx = base + j * 256 + threadIdx.x;
    s += (idx < n) ? data[idx] : 0;
  }
  red[threadIdx.x] = s;
  __syncthreads();
  for (int o = 128; o > 0; o >>= 1) {
    if (threadIdx.x < o) red[threadIdx.x] += red[threadIdx.x + o];
    __syncthreads();
  }
  if (threadIdx.x == 0) bsum[blockIdx.x] = red[0];
}

__global__ void scan_p2(int* __restrict__ bsum, int nb, int* __restrict__ off, int nscan,
                        int* __restrict__ S) {
  __shared__ int sh[128];
  int tid = threadIdx.x;
  int v = (tid < nb) ? bsum[tid] : 0;
  sh[tid] = v;
  __syncthreads();
  for (int o = 1; o < 128; o <<= 1) {
    int a = (tid >= o) ? sh[tid - o] : 0;
    __syncthreads();
    sh[tid] += a;
    __syncthreads();
  }
  if (tid < nb) bsum[tid] = sh[tid] - v;   // exclusive block bases
  if (tid == 0) { off[nscan] = sh[127]; S[NTOT] = sh[127]; }
}

__global__ void scan_p3(int* __restrict__ data, const int* __restrict__ bsum, int n) {
  __shared__ int sh[256];
  int tid = threadIdx.x;
  int base = blockIdx.x * 4096 + tid * 16;
  int vals[16];
  int s = 0;
  #pragma unroll
  for (int j = 0; j < 16; j++) {
    vals[j] = (base + j < n) ? data[base + j] : 0;
    s += vals[j];
  }
  sh[tid] = s;
  __syncthreads();
  for (int o = 1; o < 256; o <<= 1) {
    int a = (tid >= o) ? sh[tid - o] : 0;
    __syncthreads();
    sh[tid] += a;
    __syncthreads();
  }
  int run = bsum[blockIdx.x] + sh[tid] - s;
  #pragma unroll
  for (int j = 0; j < 16; j++) {
    if (base + j < n) { data[base + j] = run; run += vals[j]; }
  }
}

__global__ void scatter_ms(const int* __restrict__ s0, const int* __restrict__ s1,
                           const int* __restrict__ s2, const int* __restrict__ s3,
                           const int* __restrict__ d0, const int* __restrict__ d1,
                           const int* __restrict__ d2, const int* __restrict__ d3,
                           const int* __restrict__ off, unsigned int* __restrict__ pairs) {
  __shared__ int cur[NBUCK];
  int t = blockIdx.y, cx = blockIdx.x;
  int blk = t * CPE + cx;
  for (int i = threadIdx.x; i < NBUCK; i += 256)
    cur[i] = off[i * NBLKT + blk];
  __syncthreads();
  const int* sp = (t == 0) ? s0 : (t == 1) ? s1 : (t == 2) ? s2 : s3;
  const int* dp = (t == 0) ? d0 : (t == 1) ? d1 : (t == 2) ? d2 : d3;
  int base = cx * EPB2;
  int lim = base + EPB2; if (lim > EDGES) lim = EDGES;
  for (int i = base + threadIdx.x; i < lim; i += 256) {
    int key = t * NNODE + dp[i];
    int slot = atomicAdd(&cur[key >> BSH], 1);
    pairs[slot] = ((unsigned int)(key & 127) << 16) | (unsigned int)sp[i];
  }
}

__global__ void bucket_final(const int* __restrict__ off, const unsigned int* __restrict__ pairs,
                             int* __restrict__ S, int* __restrict__ srcs) {
  __shared__ int lcnt[128];
  __shared__ int loff[128];
  int b = blockIdx.x;
  int tid = threadIdx.x;
  int beg = off[b * NBLKT], end = off[(b + 1) * NBLKT];
  if (tid < 128) lcnt[tid] = 0;
  __syncthreads();
  for (int e = beg + tid; e < end; e += 256)
    atomicAdd(&lcnt[pairs[e] >> 16], 1);
  __syncthreads();
  int c = (tid < 128) ? lcnt[tid] : 0;
  if (tid < 128) loff[tid] = c;
  __syncthreads();
  for (int o = 1; o < 128; o <<= 1) {
    int a = (tid < 128 && tid >= o) ? loff[tid - o] : 0;
    __syncthreads();
    if (tid < 128) loff[tid] += a;
    __syncthreads();
  }
  if (tid < 128) {
    int ex = loff[tid] - c;
    int key = (b << BSH) + tid;
    if (key < NTOT) S[key] = beg + ex;
    lcnt[tid] = ex;                   // running cursor
  }
  __syncthreads();
  for (int e = beg + tid; e < end; e += 256) {
    unsigned int p = pairs[e];
    int lk = p >> 16;
    int slot = beg + atomicAdd(&lcnt[lk], 1);
    srcs[slot] = (int)(p & 0xFFFFu);
  }
}

// ---- aggregation: mean of src features per (etype, dst). Two etypes fused.
// 4-deep double-buffered software pipeline per 32-lane half; masked (predicated)
// loads; static register names only (rule #20). ~8 row-loads in flight per wave.
#define ACC8(V)                                             \
  { _Pragma("unroll")                                       \
    for (int j = 0; j < 8; j++) acc[j] += bf2f((V)[j]); }

__device__ __forceinline__ void agg_loop(const int* __restrict__ srcs, int e0, int e1,
                                         int half, int l5,
                                         const unsigned short* __restrict__ feat, float* acc) {
  int e = e0 + half;
  u16x8 z = {};
  #define LDK(K) ((e + 2*(K) < e1)                                                    \
      ? *reinterpret_cast<const u16x8*>(feat + (size_t)srcs[e + 2*(K)] * 256 + l5 * 8) \
      : z)
  u16x8 v0 = LDK(0), v1 = LDK(1), v2 = LDK(2), v3 = LDK(3);
  while (e + 8 < e1) {
    u16x8 c0 = v0, c1 = v1, c2 = v2, c3 = v3;
    e += 8;
    v0 = LDK(0); v1 = LDK(1); v2 = LDK(2); v3 = LDK(3);
    ACC8(c0); ACC8(c1); ACC8(c2); ACC8(c3);
  }
  ACC8(v0); ACC8(v1); ACC8(v2); ACC8(v3);   // masked-out slots are zero
  #undef LDK
}

__global__ __launch_bounds__(256) void agg_pair(
    const int* __restrict__ S, const int* __restrict__ srcs,
    const unsigned short* __restrict__ featA, int etA, unsigned short* __restrict__ outA,
    const unsigned short* __restrict__ featB, int etB, unsigned short* __restrict__ outB)
{
  int d = blockIdx.x * 4 + (threadIdx.x >> 6);
  int lane = threadIdx.x & 63;
  int half = lane >> 5, l5 = lane & 31;

  int gA = etA * NNODE + d;
  int a0 = S[gA], a1 = S[gA + 1];
  int gB = etB * NNODE + d;
  int b0 = S[gB], b1 = S[gB + 1];

  {
    float acc[8] = {0,0,0,0,0,0,0,0};
    agg_loop(srcs, a0, a1, half, l5, featA, acc);
    #pragma unroll
    for (int j = 0; j < 8; j++) acc[j] += __shfl_xor(acc[j], 32);
    float dA = (float)(a1 - a0); if (dA < 1.f) dA = 1.f;
    float invA = 1.f / dA;
    if (half == 0) {
      u16x8 o;
      #pragma unroll
      for (int j = 0; j < 8; j++) o[j] = f2bf(acc[j] * invA);
      *reinterpret_cast<u16x8*>(outA + (size_t)d * 256 + l5 * 8) = o;
    }
  }
  {
    float acc[8] = {0,0,0,0,0,0,0,0};
    agg_loop(srcs, b0, b1, half, l5, featB, acc);
    #pragma unroll
    for (int j = 0; j < 8; j++) acc[j] += __shfl_xor(acc[j], 32);
    float dB = (float)(b1 - b0); if (dB < 1.f) dB = 1.f;
    float invB = 1.f / dB;
    if (half == 1) {
      u16x8 o;
      #pragma unroll
      for (int j = 0; j < 8; j++) o[j] = f2bf(acc[j] * invB);
      *reinterpret_cast<u16x8*>(outB + (size_t)d * 256 + l5 * 8) = o;
    }
  }
}

// ---- stacked-K GEMM v7: C = [A0|A1](bf16 50000x512) @ WT^T + deg-masked biases.
// Both A and B staged via global_load_lds from coalesced sources, ds_read_b128
// fragments with free 2-way swizzle, double-buffered, vmcnt(6) queue discipline.
template<int MODE>
__global__ __launch_bounds__(256, 2) void gemm512(
    const unsigned short* __restrict__ A0, const unsigned short* __restrict__ A1,
    const unsigned short* __restrict__ WT,
    const float* __restrict__ bA, const float* __restrict__ bB,
    const int* __restrict__ S, int etA, int etB,
    void* __restrict__ outp, int M)
{
  __shared__ char lds[2 * 24576];     // per half: A chunk 8KB + B chunk 16KB
  int tid = threadIdx.x;
  int m0 = blockIdx.x * 128;
  int wave = tid >> 6, lane = tid & 63;
  int wr = wave >> 1, wc = wave & 1;
  int lrow = lane & 15, kgrp = lane >> 4;

  f32x4 acc[4][8];
  #pragma unroll
  for (int a = 0; a < 4; a++)
    #pragma unroll
    for (int b = 0; b < 8; b++) acc[a][b] = (f32x4){0.f, 0.f, 0.f, 0.f};

  // precomputed swizzled fragment byte offsets within a chunk-half
  int a_off[4], b_off[8];
  #pragma unroll
  for (int mb = 0; mb < 4; mb++) {
    int row = 64 * wr + 16 * mb + lrow;
    a_off[mb] = row * 64 + ((kgrp ^ ((row >> 1) & 3)) << 4);
  }
  #pragma unroll
  for (int nb = 0; nb < 8; nb++) {
    int row = 128 * wc + 16 * nb + lrow;
    b_off[nb] = 8192 + row * 64 + ((kgrp ^ ((row >> 1) & 3)) << 4);
  }

  int srow = tid >> 2;        // staging: 4 threads/row, 16B each
  int sseg = tid & 3;

  auto stage = [&](int ck) {
    char* half = lds + (ck & 1) * 24576;
    // B chunk: 256 rows x 64B (one cacheline per WT row), 4 issues
    const char* wsrc = (const char*)WT + ck * 64;
    #pragma unroll
    for (int iss = 0; iss < 4; iss++) {
      int row = iss * 64 + srow;
      int g = (row >> 1) & 3;
      const char* src = wsrc + (size_t)row * 1024 + ((sseg ^ g) << 4);
      __builtin_amdgcn_global_load_lds(
          (const AS1 unsigned int*)(const void*)src,
          (AS3 unsigned int*)(void*)(half + 8192 + iss * 4096 + tid * 16), 16, 0, 0);
    }
    // A chunk: 128 rows x 64B (contiguous 64B per row), 2 issues
    const char* asrc = (const char*)((ck < 8) ? A0 : A1) + (ck & 7) * 64;
    #pragma unroll
    for (int iss = 0; iss < 2; iss++) {
      int row = iss * 64 + srow;
      int g = (row >> 1) & 3;
      const char* src = asrc + (size_t)(m0 + row) * 512 + ((sseg ^ g) << 4);
      __builtin_amdgcn_global_load_lds(
          (const AS1 unsigned int*)(const void*)src,
          (AS3 unsigned int*)(void*)(half + iss * 4096 + tid * 16), 16, 0, 0);
    }
  };

  auto compute = [&](int ck) {
    const char* half = lds + (ck & 1) * 24576;
    bf16x8 a[4];
    #pragma unroll
    for (int mb = 0; mb < 4; mb++)
      a[mb] = *reinterpret_cast<const bf16x8*>(half + a_off[mb]);
    #pragma unroll
    for (int nb = 0; nb < 8; nb++) {
      bf16x8 b = *reinterpret_cast<const bf16x8*>(half + b_off[nb]);
      #pragma unroll
      for (int mb = 0; mb < 4; mb++)
        acc[mb][nb] = __builtin_amdgcn_mfma_f32_16x16x32_bf16(a[mb], b, acc[mb][nb], 0, 0, 0);
    }
  };

  stage(0);
  for (int ck = 0; ck < 15; ck++) {
    stage(ck + 1);                                   // queue: 6 old + 6 new
    asm volatile("s_waitcnt vmcnt(6)" ::: "memory"); // retire stage(ck) only
    asm volatile("s_barrier" ::: "memory");          // stage(ck) visible to all
    compute(ck);
    asm volatile("s_barrier" ::: "memory");          // all done reading buf[ck&1]
  }
  asm volatile("s_waitcnt vmcnt(0)" ::: "memory");
  asm volatile("s_barrier" ::: "memory");
  compute(15);

  // C/D layout: col = lane&15, row = (lane>>4)*4 + reg  [verified m89/m91]
  #pragma unroll
  for (int mb = 0; mb < 4; mb++) {
    #pragma unroll
    for (int r = 0; r < 4; r++) {
      int row = m0 + 64 * wr + 16 * mb + kgrp * 4 + r;
      if (row >= M) continue;
      int gA = etA * NNODE + row, gB = etB * NNODE + row;
      bool hA = S[gA + 1] > S[gA];   // deg>0: bias enters only via messages
      bool hB = S[gB + 1] > S[gB];
      #pragma unroll
      for (int nb = 0; nb < 8; nb++) {
        int col = 128 * wc + 16 * nb + lrow;
        float bias = (hA ? bA[col] : 0.f) + (hB ? bB[col] : 0.f);
        float v = acc[mb][nb][r] + bias;
        if (MODE == 0) {
          v = (v > 0.f) ? v : 0.01f * v;
          ((unsigned short*)outp)[(size_t)row * 256 + col] = f2bf(v);
        } else {
          ((float*)outp)[(size_t)row * 256 + col] = v;
        }
      }
    }
  }
}

extern "C" void kernel_launch(void* const* d_in, const int* in_sizes, int n_in,
                              void* d_out, int out_size, void* d_ws, size_t ws_size,
                              hipStream_t stream) {
  (void)in_sizes; (void)n_in;
  const float* chem = (const float*)d_in[0];
  const float* gene = (const float*)d_in[1];
  const float *W1[4], *B1[4], *W2[4], *B2[4];
  const int *SRC[4], *DST[4];
  // etype order: 0=ch2ge, 1=ge2ch, 2=ch2ch, 3=ge2ge
  for (int t = 0; t < 4; t++) {
    W1[t]  = (const float*)d_in[2 + 6 * t];
    B1[t]  = (const float*)d_in[3 + 6 * t];
    W2[t]  = (const float*)d_in[4 + 6 * t];
    B2[t]  = (const float*)d_in[5 + 6 * t];
    SRC[t] = (const int*)d_in[6 + 6 * t];
    DST[t] = (const int*)d_in[7 + 6 * t];
  }

  size_t off_b = 0;
  auto carve = [&](size_t bytes) -> void* {
    void* p = (char*)d_ws + off_b;
    off_b += (bytes + 255) & ~(size_t)255;
    return p;
  };
  const size_t FEAT_B = (size_t)NNODE * DIM * 2;  // 25.6 MB bf16
  unsigned short* xb_chem = (unsigned short*)carve(FEAT_B);
  unsigned short* xb_gene = (unsigned short*)carve(FEAT_B);
  unsigned short* h1_chem = (unsigned short*)carve(FEAT_B);
  unsigned short* h1_gene = (unsigned short*)carve(FEAT_B);
  unsigned short* aggA    = (unsigned short*)carve(FEAT_B);  // pairs+scan matrix aliased here
  unsigned short* aggB    = (unsigned short*)carve(FEAT_B);
  int* S    = (int*)carve(((size_t)NTOT + 1) * 4);
  int* srcs = (int*)carve((size_t)NET * EDGES * 4);
  unsigned short* WTc1 = (unsigned short*)carve((size_t)256 * 512 * 2);
  unsigned short* WTg1 = (unsigned short*)carve((size_t)256 * 512 * 2);
  unsigned short* WTc2 = (unsigned short*)carve((size_t)256 * 512 * 2);
  // aliases inside aggA (dead until after CSR build):
  unsigned int* pairs = (unsigned int*)aggA;                         // 6.4 MB
  int* cntoff = (int*)((char*)aggA + 6400000);                       // NSCAN+1 ints, in-place scan
  int* bsum   = cntoff + (NSCAN + 1);                                // 128 ints

  if (off_b > ws_size) {
    fill_f32<<<(out_size + 255) / 256, 256, 0, stream>>>((float*)d_out, (float)(ws_size >> 20), out_size);
    return;
  }

  int n4 = NNODE * DIM / 4;
  conv_f32_bf16<<<(n4 + 255) / 256, 256, 0, stream>>>(chem, xb_chem, n4);
  conv_f32_bf16<<<(n4 + 255) / 256, 256, 0, stream>>>(gene, xb_gene, n4);
  // stacked WTs: c1=(W1[1],W1[2])  g1=(W1[0],W1[3])  c2=(W2[1],W2[2])
  conv_wT3<<<dim3(256, 3), 256, 0, stream>>>(W1[1], W1[2], W1[0], W1[3], W2[1], W2[2],
                                             WTc1, WTg1, WTc2);

  // ---- multi-split CSR build ----
  dim3 cgrid(CPE, 4);
  hist_ms<<<cgrid, 256, 0, stream>>>(DST[0], DST[1], DST[2], DST[3], cntoff);
  int nb1 = (NSCAN + 4095) / 4096;   // 75
  scan_p1<<<nb1, 256, 0, stream>>>(cntoff, bsum, NSCAN);
  scan_p2<<<1, 128, 0, stream>>>(bsum, nb1, cntoff, NSCAN, S);
  scan_p3<<<nb1, 256, 0, stream>>>(cntoff, bsum, NSCAN);
  scatter_ms<<<cgrid, 256, 0, stream>>>(SRC[0], SRC[1], SRC[2], SRC[3],
                                        DST[0], DST[1], DST[2], DST[3], cntoff, pairs);
  bucket_final<<<NBUCK, 256, 0, stream>>>(cntoff, pairs, S, srcs);

  dim3 ggrid2((NNODE + 127) / 128);   // 391 blocks, full-N per block
  int nagg = NNODE / 4;               // 12500 blocks x 4 waves
  // ---- layer 1, dt=chemical: et1 (src gene) + et2 (src chem)
  agg_pair<<<nagg, 256, 0, stream>>>(S, srcs, xb_gene, 1, aggA, xb_chem, 2, aggB);
  gemm512<0><<<ggrid2, 256, 0, stream>>>(aggA, aggB, WTc1, B1[1], B1[2], S, 1, 2, h1_chem, NNODE);
  // ---- layer 1, dt=gene: et0 (src chem) + et3 (src gene)
  agg_pair<<<nagg, 256, 0, stream>>>(S, srcs, xb_chem, 0, aggA, xb_gene, 3, aggB);
  gemm512<0><<<ggrid2, 256, 0, stream>>>(aggA, aggB, WTg1, B1[0], B1[3], S, 0, 3, h1_gene, NNODE);
  // ---- layer 2, dt=chemical only: et1 (src h1_gene) + et2 (src h1_chem)
  agg_pair<<<nagg, 256, 0, stream>>>(S, srcs, h1_gene, 1, aggA, h1_chem, 2, aggB);
  gemm512<1><<<ggrid2, 256, 0, stream>>>(aggA, aggB, WTc2, B2[1], B2[2], S, 1, 2, d_out, NNODE);
}